// Round 9
// baseline (436.942 us; speedup 1.0000x reference)
//
#include <hip/hip_runtime.h>
#include <stdint.h>

typedef int v4i __attribute__((ext_vector_type(4)));
typedef int v16i __attribute__((ext_vector_type(16)));

__device__ __forceinline__ int clamp_i8(int v) {
    return v < -128 ? -128 : (v > 127 ? 127 : v);
}

// ---------------- pre-pass 1: quantize fp32 input -> int8 A-FRAGMENTS -------
// A-fragment layout (mirror of the R7-verified B layout): fragment
// t = ((r32 * (K/32) + k32) * 64 + lane), 16 bytes, holding
// row = r32*32 + (lane&31), k = k32*32 + (lane>>5)*16 + 0..15 — the exact
// mfma_i32_32x32x32_i8 A-operand identity [m = lane&31][k = (lane>>5)*16+j].
// Each thread reads one full 64B cache line (4 x float4) and writes 16B
// packed — write perfectly coalesced, read line-resident in L1.
__global__ void quant_input_kernel(const float* __restrict__ x, int4* __restrict__ q,
                                   const float* __restrict__ scale_p,
                                   const int* __restrict__ zp_p, int K, int nfrag) {
    const float inv = 1.0f / *scale_p;
    const int zp = *zp_p;
    const int Kc32 = K / 32;
    const int stride = gridDim.x * blockDim.x;
    for (int t = blockIdx.x * blockDim.x + threadIdx.x; t < nfrag; t += stride) {
        const int l = t & 63;
        const int rest = t >> 6;
        const int k32 = rest % Kc32;
        const int r32 = rest / Kc32;
        const int row = r32 * 32 + (l & 31);
        const int kb = k32 * 32 + (l >> 5) * 16;
        const float* src = x + (int64_t)row * K + kb;
        int4 out;
        int* op = (int*)&out;
#pragma unroll
        for (int j = 0; j < 4; j++) {
            float4 v = *(const float4*)(src + 4 * j);
            int q0 = clamp_i8((int)rintf(v.x * inv) + zp);
            int q1 = clamp_i8((int)rintf(v.y * inv) + zp);
            int q2 = clamp_i8((int)rintf(v.z * inv) + zp);
            int q3 = clamp_i8((int)rintf(v.w * inv) + zp);
            op[j] = (q0 & 255) | ((q1 & 255) << 8) | ((q2 & 255) << 16) | ((q3 & 255) << 24);
        }
        q[t] = out;
    }
}

// ---------------- pre-pass 2: pack int32 weight -> int8 B-FRAGMENTS ---------
// (verified R7/R8, absmax 0) fragment t = ((c32*(K/32) + k32)*64 + lane),
// col = c32*32 + (lane&31), k = k32*32 + (lane>>5)*16 + 0..15.
__global__ void pack_weight_kernel(const int* __restrict__ w, int4* __restrict__ q,
                                   int K, int nfrag) {
    const int stride = gridDim.x * blockDim.x;
    const int Kc32 = K / 32;
    for (int t = blockIdx.x * blockDim.x + threadIdx.x; t < nfrag; t += stride) {
        const int l = t & 63;
        const int rest = t >> 6;
        const int k32 = rest % Kc32;
        const int c32 = rest / Kc32;
        const int col = c32 * 32 + (l & 31);
        const int kb = k32 * 32 + (l >> 5) * 16;
        const int* src = w + (int64_t)col * K + kb;
        int4 out;
        int* op = (int*)&out;
#pragma unroll
        for (int j = 0; j < 4; j++) {
            int4 v = *(const int4*)(src + 4 * j);
            op[j] = (v.x & 255) | ((v.y & 255) << 8) | ((v.z & 255) << 16) | ((v.w & 255) << 24);
        }
        q[t] = out;
    }
}

// ---------------- main GEMM: C[i][j] = sum_k A[i][k] * W[j][k] ----------------
// ROUND 9: BARRIER-FREE register-streaming GEMM. Eight rounds of evidence:
// every LDS+barrier structure (2/3-buffer, counted vmcnt, 8-phase, 3/SIMD)
// lands at 157-185us, MfmaUtil 33-41% — the per-tile barrier/LDS cycle is the
// invariant cost, and i8 32x32x32 needs 224 B/cy of fragments vs the LDS
// pipe's 128 B/cy unless reuse is huge (which blows registers, R5).
// Fix: BOTH operands pre-packed in MFMA fragment order by the pre-passes;
// the GEMM is a pure stream: 12 global b128 loads + 16 MFMA per K-tile per
// wave. NO LDS, NO __syncthreads. Block 256x256, 8 waves (2Mx4N), wave tile
// 128x64: acc 128 + frags 48 + addr ~30 => ~206 < 256 regs -> 2 waves/SIMD.
// Waves sharing wm read IDENTICAL A-frags (L1 dedup); ws sharing wn dedup B.
// A+B packed (48MB) fit L3; XCD swizzle gives each XCD 4 row-strips (4MB A)
// for L2 residency. Expected bound: MFMA (62us) to L2-BW (~95us).
#define BM 256
#define BN 256
#define BK 64

__global__ __launch_bounds__(512, 2) void gemm_i8_kernel(
    const int8_t* __restrict__ A, const int8_t* __restrict__ W,
    const int* __restrict__ bias, int* __restrict__ C,
    const float* __restrict__ oscale_p, const int* __restrict__ ozp_p,
    int N, int K, int M) {
    const int tid = threadIdx.x;
    const int lane = tid & 63;
    const int w = tid >> 6;   // wave 0..7
    const int wm = w >> 2;    // wave row (0..1) -> rows wm*128
    const int wn = w & 3;     // wave col (0..3) -> cols wn*64

    // --- XCD-bijective block swizzle: 64 consecutive slots per XCD
    // (= 4 full row-strips of 16 col-blocks -> 4MB of A resident per L2).
    const int nwg = gridDim.x;            // 512 for 8192x4096
    const int mblocks = M / BN;           // 16
    int bid = blockIdx.x;
    if ((nwg & 7) == 0) bid = (bid & 7) * (nwg >> 3) + (bid >> 3);
    const int by = bid / mblocks;
    const int bx = bid % mblocks;
    const int bm = by * BM;
    const int bn = bx * BN;

    const int Kc32 = K >> 5;

    // --- fragment pointers (advance 2048B per BK=64 tile)
    const int8_t* pA[4];
#pragma unroll
    for (int ms = 0; ms < 4; ms++) {
        const int r32 = (bm >> 5) + wm * 4 + ms;
        pA[ms] = A + ((int64_t)r32 * Kc32 * 64 + lane) * 16;
    }
    const int8_t* pB[2];
#pragma unroll
    for (int ns = 0; ns < 2; ns++) {
        const int c32 = (bn >> 5) + wn * 2 + ns;
        pB[ns] = W + ((int64_t)c32 * Kc32 * 64 + lane) * 16;
    }

    v16i acc[4][2];
#pragma unroll
    for (int i = 0; i < 4; i++)
#pragma unroll
        for (int j = 0; j < 2; j++)
#pragma unroll
            for (int r = 0; r < 16; r++) acc[i][j][r] = 0;

    v4i af[4][2], bf[2][2];  // [group][k32-half], single set (reg budget)

#define LOADF                                                   \
    do {                                                        \
        _Pragma("unroll") for (int ms = 0; ms < 4; ms++) {      \
            af[ms][0] = *(const v4i*)(pA[ms]);                  \
            af[ms][1] = *(const v4i*)(pA[ms] + 1024);           \
            pA[ms] += 2048;                                     \
        }                                                       \
        _Pragma("unroll") for (int ns = 0; ns < 2; ns++) {      \
            bf[ns][0] = *(const v4i*)(pB[ns]);                  \
            bf[ns][1] = *(const v4i*)(pB[ns] + 1024);           \
            pB[ns] += 2048;                                     \
        }                                                       \
    } while (0)

#define MFMA_ALL                                                              \
    do {                                                                      \
        _Pragma("unroll") for (int ms = 0; ms < 4; ms++)                      \
            _Pragma("unroll") for (int ns = 0; ns < 2; ns++)                  \
                _Pragma("unroll") for (int kh = 0; kh < 2; kh++)              \
                    acc[ms][ns] = __builtin_amdgcn_mfma_i32_32x32x32_i8(      \
                        af[ms][kh], bf[ns][kh], acc[ms][ns], 0, 0, 0);        \
    } while (0)

    const int NT = K / BK;  // 64
    LOADF;                  // tile 0
    for (int kt = 0; kt < NT - 1; ++kt) {
        MFMA_ALL;  // compiler interleaves next loads as frag regs retire (WAR)
        LOADF;
    }
    MFMA_ALL;

#undef LOADF
#undef MFMA_ALL

    // --- epilogue: requantize, store int32
    // C/D layout (32x32): col = lane&31, row = (reg&3) + 8*(reg>>2) + 4*(lane>>5)
    const int m0 = lane & 31;
    const float inv_os = 1.0f / *oscale_p;
    const int ozp = *ozp_p;
    const int rbase = 4 * (lane >> 5);
#pragma unroll
    for (int ns = 0; ns < 2; ns++) {
        const int gn = bn + wn * 64 + ns * 32 + m0;
        const int bv = bias[gn];
#pragma unroll
        for (int ms = 0; ms < 4; ms++) {
            const int gm0 = bm + wm * 128 + ms * 32 + rbase;
            v16i a = acc[ms][ns];
#pragma unroll
            for (int reg = 0; reg < 16; reg++) {
                const int row = (reg & 3) + 8 * (reg >> 2);
                int v = a[reg] + bv;
                int q = (int)rintf((float)v * inv_os) + ozp;
                q = clamp_i8(q);
                C[(int64_t)(gm0 + row) * M + gn] = q;
            }
        }
    }
}

extern "C" void kernel_launch(void* const* d_in, const int* in_sizes, int n_in,
                              void* d_out, int out_size, void* d_ws, size_t ws_size,
                              hipStream_t stream) {
    const float* x = (const float*)d_in[0];
    const int* wgt = (const int*)d_in[1];
    const int* bias = (const int*)d_in[2];
    const float* in_scale = (const float*)d_in[3];
    const int* in_zp = (const int*)d_in[4];
    const float* out_scale = (const float*)d_in[5];
    const int* out_zp = (const int*)d_in[6];

    const int64_t x_elems = (int64_t)in_sizes[0];  // N*K
    const int OUT = in_sizes[2];                   // bias length
    const int K = in_sizes[1] / OUT;               // IN
    const int N = (int)(x_elems / K);

    int8_t* qA = (int8_t*)d_ws;
    int8_t* qW = qA + x_elems;

    {
        int nfrag = (int)(x_elems / 16);           // A fragments
        quant_input_kernel<<<4096, 256, 0, stream>>>(
            x, (int4*)qA, in_scale, in_zp, K, nfrag);
    }
    {
        int nfrag = (int)(((int64_t)OUT * K) / 16);  // B fragments
        pack_weight_kernel<<<2048, 256, 0, stream>>>(
            (const int*)wgt, (int4*)qW, K, nfrag);
    }
    const int nblocks = (OUT / BN) * (N / BM);     // 16 x 32 = 512
    gemm_i8_kernel<<<dim3(nblocks), 512, 0, stream>>>(
        qA, qW, bias, (int*)d_out, out_scale, out_zp, N, K, OUT);
}